// Round 13
// baseline (187.491 us; speedup 1.0000x reference)
//
#include <hip/hip_runtime.h>
#include <stdint.h>

// Problem constants (B=8, T=2048, D=256, K=8192)
#define M_TOK 16384
#define DIM   256
#define KCB   8192
#define NGRP  8                    // N-groups (blocks in y)
#define GRP   1024                 // codes per group
#define NCHK  16                   // 16B fp8 k-chunks per row (256*1B/16B)
#define NT    16                   // 64-code tiles per group
#define SHIFT 512.0f               // positivity shift for score packing
#define INV_N (1.0f / 4194304.0f)  // 1/(B*T*D)
#define SC1   0x7F7F7F7F           // E8M0 scale bytes = 2^0 (op_sel-proof)

typedef __attribute__((ext_vector_type(4))) float f32x4;
typedef __attribute__((ext_vector_type(8))) int   i32x8;

// Async global->LDS DMA, 16 B/lane; LDS dest = wave-uniform base + lane*16.
static __device__ __forceinline__ void lds_cp16(const void* g, void* l) {
    __builtin_amdgcn_global_load_lds(
        (const __attribute__((address_space(1))) void*)g,
        (__attribute__((address_space(3))) void*)l, 16, 0, 0);
}

// pack 4 floats -> 4 fp8 e4m3 bytes (one dword)
static __device__ __forceinline__ int pk4(float4 f) {
    int o = __builtin_amdgcn_cvt_pk_fp8_f32(f.x, f.y, 0, false);
    o     = __builtin_amdgcn_cvt_pk_fp8_f32(f.z, f.w, o, true);
    return o;
}

// ---------------------------------------------------------------- kernel 1
// Codebook prep: cbt[chunk][code][16B] = fp8 of -c, k-chunk-major (GEMM LDS
// staging reads 1KB-contiguous); chalf = 0.5||c||^2 + SHIFT (exact fp32).
// Block = 64 codes; wave w handles k-chunks [4w, 4w+4); lane = code.
__global__ void k_prep(const float* __restrict__ cb,
                       unsigned char* __restrict__ cbt,
                       float* __restrict__ chalf) {
    __shared__ float part[4][64];
    const int w  = threadIdx.x >> 6;
    const int l  = threadIdx.x & 63;
    const int c0 = blockIdx.x * 64;
    const float* row = cb + (size_t)(c0 + l) * DIM;
    float s = 0.0f;
    #pragma unroll
    for (int j = 0; j < 4; j++) {
        int ch = w * 4 + j;
        const float* p = row + ch * 16;
        float4 a = *(const float4*)(p);
        float4 b = *(const float4*)(p + 4);
        float4 c = *(const float4*)(p + 8);
        float4 d = *(const float4*)(p + 12);
        s += a.x*a.x + a.y*a.y + a.z*a.z + a.w*a.w
           + b.x*b.x + b.y*b.y + b.z*b.z + b.w*b.w
           + c.x*c.x + c.y*c.y + c.z*c.z + c.w*c.w
           + d.x*d.x + d.y*d.y + d.z*d.z + d.w*d.w;
        float4 na = {-a.x, -a.y, -a.z, -a.w};
        float4 nb = {-b.x, -b.y, -b.z, -b.w};
        float4 nc = {-c.x, -c.y, -c.z, -c.w};
        float4 nd = {-d.x, -d.y, -d.z, -d.w};
        uint4 r;
        r.x = (unsigned)pk4(na); r.y = (unsigned)pk4(nb);
        r.z = (unsigned)pk4(nc); r.w = (unsigned)pk4(nd);
        *(uint4*)(cbt + ((size_t)ch * KCB + c0 + l) * 16) = r;
    }
    part[w][l] = s;
    __syncthreads();
    if (w == 0) {
        float t = part[0][l] + part[1][l] + part[2][l] + part[3][l];
        chalf[c0 + l] = 0.5f * t + SHIFT;
    }
}

// ---------------------------------------------------------------- kernel 2
// fp8-MX double-buffered GEMM+argmin. R13 change: wave = 64 rows x 32 codes
// (rh = w>>1, code-half = w&1; rt=4, ct=2). R12's wave read the full 16 KB
// B tile (LDS pipe 20.5 us = top pipe); halving codes/wave halves LDS reads
// while keeping MFMA count and the 4-blocks/CU occupancy. Two code-half
// waves merge keys via skey[128][2] at the end.
__global__ __launch_bounds__(256, 4) void k_gemm_argmin(
    const float* __restrict__ xs,              // [M_TOK][DIM] fp32
    const unsigned char* __restrict__ cbt,     // [NCHK][KCB][16] fp8 of -c
    const float* __restrict__ chalf,           // [KCB] = 0.5||c||^2+SHIFT
    uint32_t* __restrict__ pkey)               // [M_TOK][NGRP]
{
    __shared__ __align__(16) unsigned char Bs[2][NCHK][64][16];   // 32 KB
    __shared__ float schalf[GRP];                                  // 4 KB
    __shared__ uint32_t skey[128][2];                              // 1 KB

    const int tid  = threadIdx.x;
    const int w    = tid >> 6;
    const int l    = tid & 63;
    const int lrow = l & 15;          // code index within a 16-col MFMA tile
    const int quad = l >> 4;          // k-segment / acc row group
    const int rh   = w >> 1;          // row half (64 rows each)
    const int chh  = w & 1;           // code half (32 codes each)
    const int m0 = blockIdx.x * 128;
    const int g  = blockIdx.y;

    *(float4*)&schalf[tid * 4] = ((const float4*)(chalf + g * GRP))[tid];

    // staging: wave w supplies chunks [4w,4w+4); lane = code in tile
    const unsigned char* bsrc = cbt + ((size_t)(w * 4) * KCB + g * GRP + l) * 16;

    #pragma unroll
    for (int j = 0; j < 4; j++)
        lds_cp16(bsrc + (size_t)j * KCB * 16, &Bs[0][w * 4 + j][0][0]);

    // ---- A panel: 64 rows x 256 k, fp32 -> fp8 frags (4 rt x 2 ks x 8 dw)
    i32x8 afr[4][2];
    {
        const float* ap = xs + (size_t)(m0 + rh * 64 + lrow) * DIM + quad * 32;
        #pragma unroll
        for (int rt = 0; rt < 4; rt++)
            #pragma unroll
            for (int ks = 0; ks < 2; ks++) {
                const float* p = ap + rt * 16 * DIM + ks * 128;
                union { int d[8]; i32x8 v; } aa;
                #pragma unroll
                for (int d = 0; d < 8; d++)
                    aa.d[d] = pk4(*(const float4*)(p + d * 4));
                afr[rt][ks] = aa.v;
            }
    }

    uint32_t best[4][4];
    #pragma unroll
    for (int rt = 0; rt < 4; rt++)
        #pragma unroll
        for (int rg = 0; rg < 4; rg++) best[rt][rg] = 0xFFFFFFFFu;

    #pragma unroll 1
    for (int t = 0; t < NT; t++) {
        const int cur = t & 1;
        __syncthreads();   // drains DMA(t) issued one compute phase ago
        if (t < NT - 1) {  // prefetch t+1 AFTER the barrier
            #pragma unroll
            for (int j = 0; j < 4; j++)
                lds_cp16(bsrc + ((size_t)j * KCB + (t + 1) * 64) * 16,
                         &Bs[1 - cur][w * 4 + j][0][0]);
        }

        f32x4 acc[4][2];
        #pragma unroll
        for (int ct = 0; ct < 2; ct++) {
            float cs = schalf[t * 64 + chh * 32 + ct * 16 + lrow];
            #pragma unroll
            for (int rt = 0; rt < 4; rt++) {
                f32x4 c4 = {cs, cs, cs, cs};
                acc[rt][ct] = c4;
            }
        }
        #pragma unroll
        for (int ks = 0; ks < 2; ks++) {
            const int ch = ks * 8 + quad * 2;   // lane's k-window = 2 chunks
            i32x8 bfr[2];
            #pragma unroll
            for (int ct = 0; ct < 2; ct++) {
                union { uint4 q[2]; i32x8 v; } bb;
                bb.q[0] = *(const uint4*)&Bs[cur][ch][chh * 32 + ct * 16 + lrow][0];
                bb.q[1] = *(const uint4*)&Bs[cur][ch + 1][chh * 32 + ct * 16 + lrow][0];
                bfr[ct] = bb.v;
            }
            #pragma unroll
            for (int rt = 0; rt < 4; rt++)
                #pragma unroll
                for (int ct = 0; ct < 2; ct++)
                    acc[rt][ct] = __builtin_amdgcn_mfma_scale_f32_16x16x128_f8f6f4(
                        afr[rt][ks], bfr[ct], acc[rt][ct],
                        0, 0,              // cbsz, blgp: fmt 0 = fp8 e4m3
                        0, SC1,            // op_sel_a, scale_a = 2^0
                        0, SC1);           // op_sel_b, scale_b = 2^0
        }
        // fold scores into packed keys: (score_bits & ~1023) | group-local id
        #pragma unroll
        for (int ct = 0; ct < 2; ct++) {
            uint32_t idl = (uint32_t)(t * 64 + chh * 32 + ct * 16 + lrow);
            #pragma unroll
            for (int rt = 0; rt < 4; rt++)
                #pragma unroll
                for (int rg = 0; rg < 4; rg++) {
                    uint32_t key =
                        (__float_as_uint(acc[rt][ct][rg]) & 0xFFFFFC00u) | idl;
                    if (key < best[rt][rg]) best[rt][rg] = key;
                }
        }
    }

    // min across the 16 lanes of each quad group (same rows, different codes)
    #pragma unroll
    for (int off = 1; off < 16; off <<= 1)
        #pragma unroll
        for (int rt = 0; rt < 4; rt++)
            #pragma unroll
            for (int rg = 0; rg < 4; rg++) {
                uint32_t o = __shfl_xor(best[rt][rg], off);
                if (o < best[rt][rg]) best[rt][rg] = o;
            }
    if (lrow == 0) {
        #pragma unroll
        for (int rt = 0; rt < 4; rt++)
            #pragma unroll
            for (int rg = 0; rg < 4; rg++)
                skey[rh * 64 + rt * 16 + quad * 4 + rg][chh] = best[rt][rg];
    }
    __syncthreads();
    if (tid < 128) {
        uint32_t k0 = skey[tid][0], k1 = skey[tid][1];
        pkey[(size_t)(m0 + tid) * NGRP + g] = k0 < k1 ? k0 : k1;
    }
}

// ---------------------------------------------------------------- kernel 3
// Per row: min over 8 group keys -> final code; exact fp32 ||x-c||^2;
// per-block LDS reduce -> partial[blockIdx]. No global atomics/fences.
__global__ void k_finalize(const uint32_t* __restrict__ pkey,
                           const float4* __restrict__ xs4,
                           const float4* __restrict__ cb4,
                           float* __restrict__ partial) {
    __shared__ float sblk[4];
    int w   = threadIdx.x >> 6;
    int row = blockIdx.x * 4 + w;
    int l   = threadIdx.x & 63;
    uint32_t k = 0xFFFFFFFFu;
    int g = 0;
    if (l < 8) { k = pkey[(size_t)row * NGRP + l]; g = l; }
    #pragma unroll
    for (int off = 1; off < 8; off <<= 1) {
        uint32_t ok = __shfl_xor(k, off);
        int      og = __shfl_xor(g, off);
        if (ok < k) { k = ok; g = og; }
    }
    k = __shfl(k, 0);
    g = __shfl(g, 0);
    int code = g * GRP + (int)(k & 1023u);
    float4 x = xs4[(size_t)row * 64 + l];
    float4 c = cb4[(size_t)code * 64 + l];
    float dx = x.x - c.x, dy = x.y - c.y, dz = x.z - c.z, dw = x.w - c.w;
    float s = dx * dx + dy * dy + dz * dz + dw * dw;
    #pragma unroll
    for (int off = 32; off; off >>= 1) s += __shfl_xor(s, off);
    if (l == 0) sblk[w] = s;
    __syncthreads();
    if (threadIdx.x == 0)
        partial[blockIdx.x] = sblk[0] + sblk[1] + sblk[2] + sblk[3];
}

// ---------------------------------------------------------------- kernel 4
__global__ void k_write(const float* __restrict__ partial,
                        float* __restrict__ out) {
    __shared__ float swv[16];
    int tid = threadIdx.x;                    // 1024 threads = 16 waves
    float s = partial[tid] + partial[tid + 1024] +
              partial[tid + 2048] + partial[tid + 3072];
    #pragma unroll
    for (int off = 32; off; off >>= 1) s += __shfl_xor(s, off);
    if ((tid & 63) == 0) swv[tid >> 6] = s;
    __syncthreads();
    if (tid == 0) {
        float t = 0.0f;
        #pragma unroll
        for (int i = 0; i < 16; i++) t += swv[i];
        float commit = t * INV_N;
        out[0] = 0.25f * commit;   // loss
        out[1] = commit;           // commit_loss
    }
}

extern "C" void kernel_launch(void* const* d_in, const int* in_sizes, int n_in,
                              void* d_out, int out_size, void* d_ws, size_t ws_size,
                              hipStream_t stream) {
    const float* xs = (const float*)d_in[0];
    // d_in[1] = ilens (int64, all == T) -> slice is a no-op, unused
    const float* cb = (const float*)d_in[2];

    char* ws = (char*)d_ws;
    unsigned char* cbt     = (unsigned char*)(ws + 256);            // 2 MiB
    float*         chalf   = (float*)(ws + 256 + 2097152);          // 32 KiB
    uint32_t*      pkey    = (uint32_t*)(ws + 256 + 2129920);       // 512 KiB
    float*         partial = (float*)(ws + 256 + 2654208);          // 16 KiB

    k_prep<<<128, 256, 0, stream>>>(cb, cbt, chalf);
    dim3 g(M_TOK / 128, NGRP);
    k_gemm_argmin<<<g, 256, 0, stream>>>(xs, cbt, chalf, pkey);
    k_finalize<<<4096, 256, 0, stream>>>(pkey, (const float4*)xs,
                                         (const float4*)cb, partial);
    k_write<<<1, 1024, 0, stream>>>(partial, (float*)d_out);
}

// Round 14
// 134.520 us; speedup vs baseline: 1.3938x; 1.3938x over previous
//
#include <hip/hip_runtime.h>
#include <stdint.h>

// Problem constants (B=8, T=2048, D=256, K=8192)
#define M_TOK 16384
#define DIM   256
#define KCB   8192
#define NGRP  8                    // N-groups (blocks in y)
#define GRP   1024                 // codes per group
#define NCHK  16                   // 16B fp8 k-chunks per row (256*1B/16B)
#define NT    16                   // 64-code tiles per group
#define SHIFT 512.0f               // positivity shift for score packing
#define INV_N (1.0f / 4194304.0f)  // 1/(B*T*D)
#define SC1   0x7F7F7F7F           // E8M0 scale bytes = 2^0 (op_sel-proof)

typedef __attribute__((ext_vector_type(4))) float f32x4;
typedef __attribute__((ext_vector_type(8))) int   i32x8;

// Async global->LDS DMA, 16 B/lane; LDS dest = wave-uniform base + lane*16.
static __device__ __forceinline__ void lds_cp16(const void* g, void* l) {
    __builtin_amdgcn_global_load_lds(
        (const __attribute__((address_space(1))) void*)g,
        (__attribute__((address_space(3))) void*)l, 16, 0, 0);
}

// pack 4 floats -> 4 fp8 e4m3 bytes (one dword)
static __device__ __forceinline__ int pk4(float4 f) {
    int o = __builtin_amdgcn_cvt_pk_fp8_f32(f.x, f.y, 0, false);
    o     = __builtin_amdgcn_cvt_pk_fp8_f32(f.z, f.w, o, true);
    return o;
}

// ---------------------------------------------------------------- kernel 1
// Codebook prep: cbt[chunk][code][16B] = fp8 of -c, k-chunk-major (GEMM LDS
// staging reads 1KB-contiguous); chalf = 0.5||c||^2 + SHIFT (exact fp32).
// Block = 64 codes; wave w handles k-chunks [4w, 4w+4); lane = code.
__global__ void k_prep(const float* __restrict__ cb,
                       unsigned char* __restrict__ cbt,
                       float* __restrict__ chalf) {
    __shared__ float part[4][64];
    const int w  = threadIdx.x >> 6;
    const int l  = threadIdx.x & 63;
    const int c0 = blockIdx.x * 64;
    const float* row = cb + (size_t)(c0 + l) * DIM;
    float s = 0.0f;
    #pragma unroll
    for (int j = 0; j < 4; j++) {
        int ch = w * 4 + j;
        const float* p = row + ch * 16;
        float4 a = *(const float4*)(p);
        float4 b = *(const float4*)(p + 4);
        float4 c = *(const float4*)(p + 8);
        float4 d = *(const float4*)(p + 12);
        s += a.x*a.x + a.y*a.y + a.z*a.z + a.w*a.w
           + b.x*b.x + b.y*b.y + b.z*b.z + b.w*b.w
           + c.x*c.x + c.y*c.y + c.z*c.z + c.w*c.w
           + d.x*d.x + d.y*d.y + d.z*d.z + d.w*d.w;
        float4 na = {-a.x, -a.y, -a.z, -a.w};
        float4 nb = {-b.x, -b.y, -b.z, -b.w};
        float4 nc = {-c.x, -c.y, -c.z, -c.w};
        float4 nd = {-d.x, -d.y, -d.z, -d.w};
        uint4 r;
        r.x = (unsigned)pk4(na); r.y = (unsigned)pk4(nb);
        r.z = (unsigned)pk4(nc); r.w = (unsigned)pk4(nd);
        *(uint4*)(cbt + ((size_t)ch * KCB + c0 + l) * 16) = r;
    }
    part[w][l] = s;
    __syncthreads();
    if (w == 0) {
        float t = part[0][l] + part[1][l] + part[2][l] + part[3][l];
        chalf[c0 + l] = 0.5f * t + SHIFT;
    }
}

// ---------------------------------------------------------------- kernel 2
// fp8-MX double-buffered GEMM+argmin. Wave = 64 rows x 32 codes (rt=4,
// ct=2) — halves per-FLOP LDS reads vs the 32-row wave (R12). R13 POST-
// MORTEM: __launch_bounds__(256,4) capped the unified RF at 128 (split
// 64 arch + 64 acc); the 64-row A panel needs ~105 arch regs -> spilled to
// scratch (WRITE_SIZE 76 MB, MfmaUtil 11%). Fix: min-waves 3 -> 170-reg
// budget, A panel stays resident; 3 blocks/CU (LDS 37 KB x 3 = 111 KB).
__global__ __launch_bounds__(256, 3) void k_gemm_argmin(
    const float* __restrict__ xs,              // [M_TOK][DIM] fp32
    const unsigned char* __restrict__ cbt,     // [NCHK][KCB][16] fp8 of -c
    const float* __restrict__ chalf,           // [KCB] = 0.5||c||^2+SHIFT
    uint32_t* __restrict__ pkey)               // [M_TOK][NGRP]
{
    __shared__ __align__(16) unsigned char Bs[2][NCHK][64][16];   // 32 KB
    __shared__ float schalf[GRP];                                  // 4 KB
    __shared__ uint32_t skey[128][2];                              // 1 KB

    const int tid  = threadIdx.x;
    const int w    = tid >> 6;
    const int l    = tid & 63;
    const int lrow = l & 15;          // code index within a 16-col MFMA tile
    const int quad = l >> 4;          // k-segment / acc row group
    const int rh   = w >> 1;          // row half (64 rows each)
    const int chh  = w & 1;           // code half (32 codes each)
    const int m0 = blockIdx.x * 128;
    const int g  = blockIdx.y;

    *(float4*)&schalf[tid * 4] = ((const float4*)(chalf + g * GRP))[tid];

    // staging: wave w supplies chunks [4w,4w+4); lane = code in tile
    const unsigned char* bsrc = cbt + ((size_t)(w * 4) * KCB + g * GRP + l) * 16;

    #pragma unroll
    for (int j = 0; j < 4; j++)
        lds_cp16(bsrc + (size_t)j * KCB * 16, &Bs[0][w * 4 + j][0][0]);

    // ---- A panel: 64 rows x 256 k, fp32 -> fp8 frags (4 rt x 2 ks x 8 dw)
    i32x8 afr[4][2];
    {
        const float* ap = xs + (size_t)(m0 + rh * 64 + lrow) * DIM + quad * 32;
        #pragma unroll
        for (int rt = 0; rt < 4; rt++)
            #pragma unroll
            for (int ks = 0; ks < 2; ks++) {
                const float* p = ap + rt * 16 * DIM + ks * 128;
                union { int d[8]; i32x8 v; } aa;
                #pragma unroll
                for (int d = 0; d < 8; d++)
                    aa.d[d] = pk4(*(const float4*)(p + d * 4));
                afr[rt][ks] = aa.v;
            }
    }

    uint32_t best[4][4];
    #pragma unroll
    for (int rt = 0; rt < 4; rt++)
        #pragma unroll
        for (int rg = 0; rg < 4; rg++) best[rt][rg] = 0xFFFFFFFFu;

    #pragma unroll 1
    for (int t = 0; t < NT; t++) {
        const int cur = t & 1;
        __syncthreads();   // drains DMA(t) issued one compute phase ago
        if (t < NT - 1) {  // prefetch t+1 AFTER the barrier
            #pragma unroll
            for (int j = 0; j < 4; j++)
                lds_cp16(bsrc + ((size_t)j * KCB + (t + 1) * 64) * 16,
                         &Bs[1 - cur][w * 4 + j][0][0]);
        }

        f32x4 acc[4][2];
        #pragma unroll
        for (int ct = 0; ct < 2; ct++) {
            float cs = schalf[t * 64 + chh * 32 + ct * 16 + lrow];
            #pragma unroll
            for (int rt = 0; rt < 4; rt++) {
                f32x4 c4 = {cs, cs, cs, cs};
                acc[rt][ct] = c4;
            }
        }
        #pragma unroll
        for (int ks = 0; ks < 2; ks++) {
            const int ch = ks * 8 + quad * 2;   // lane's k-window = 2 chunks
            i32x8 bfr[2];
            #pragma unroll
            for (int ct = 0; ct < 2; ct++) {
                union { uint4 q[2]; i32x8 v; } bb;
                bb.q[0] = *(const uint4*)&Bs[cur][ch][chh * 32 + ct * 16 + lrow][0];
                bb.q[1] = *(const uint4*)&Bs[cur][ch + 1][chh * 32 + ct * 16 + lrow][0];
                bfr[ct] = bb.v;
            }
            #pragma unroll
            for (int rt = 0; rt < 4; rt++)
                #pragma unroll
                for (int ct = 0; ct < 2; ct++)
                    acc[rt][ct] = __builtin_amdgcn_mfma_scale_f32_16x16x128_f8f6f4(
                        afr[rt][ks], bfr[ct], acc[rt][ct],
                        0, 0,              // cbsz, blgp: fmt 0 = fp8 e4m3
                        0, SC1,            // op_sel_a, scale_a = 2^0
                        0, SC1);           // op_sel_b, scale_b = 2^0
        }
        // fold scores into packed keys: (score_bits & ~1023) | group-local id
        #pragma unroll
        for (int ct = 0; ct < 2; ct++) {
            uint32_t idl = (uint32_t)(t * 64 + chh * 32 + ct * 16 + lrow);
            #pragma unroll
            for (int rt = 0; rt < 4; rt++)
                #pragma unroll
                for (int rg = 0; rg < 4; rg++) {
                    uint32_t key =
                        (__float_as_uint(acc[rt][ct][rg]) & 0xFFFFFC00u) | idl;
                    if (key < best[rt][rg]) best[rt][rg] = key;
                }
        }
    }

    // min across the 16 lanes of each quad group (same rows, different codes)
    #pragma unroll
    for (int off = 1; off < 16; off <<= 1)
        #pragma unroll
        for (int rt = 0; rt < 4; rt++)
            #pragma unroll
            for (int rg = 0; rg < 4; rg++) {
                uint32_t o = __shfl_xor(best[rt][rg], off);
                if (o < best[rt][rg]) best[rt][rg] = o;
            }
    if (lrow == 0) {
        #pragma unroll
        for (int rt = 0; rt < 4; rt++)
            #pragma unroll
            for (int rg = 0; rg < 4; rg++)
                skey[rh * 64 + rt * 16 + quad * 4 + rg][chh] = best[rt][rg];
    }
    __syncthreads();
    if (tid < 128) {
        uint32_t k0 = skey[tid][0], k1 = skey[tid][1];
        pkey[(size_t)(m0 + tid) * NGRP + g] = k0 < k1 ? k0 : k1;
    }
}

// ---------------------------------------------------------------- kernel 3
// Per row: min over 8 group keys -> final code; exact fp32 ||x-c||^2;
// per-block LDS reduce -> partial[blockIdx]. No global atomics/fences.
__global__ void k_finalize(const uint32_t* __restrict__ pkey,
                           const float4* __restrict__ xs4,
                           const float4* __restrict__ cb4,
                           float* __restrict__ partial) {
    __shared__ float sblk[4];
    int w   = threadIdx.x >> 6;
    int row = blockIdx.x * 4 + w;
    int l   = threadIdx.x & 63;
    uint32_t k = 0xFFFFFFFFu;
    int g = 0;
    if (l < 8) { k = pkey[(size_t)row * NGRP + l]; g = l; }
    #pragma unroll
    for (int off = 1; off < 8; off <<= 1) {
        uint32_t ok = __shfl_xor(k, off);
        int      og = __shfl_xor(g, off);
        if (ok < k) { k = ok; g = og; }
    }
    k = __shfl(k, 0);
    g = __shfl(g, 0);
    int code = g * GRP + (int)(k & 1023u);
    float4 x = xs4[(size_t)row * 64 + l];
    float4 c = cb4[(size_t)code * 64 + l];
    float dx = x.x - c.x, dy = x.y - c.y, dz = x.z - c.z, dw = x.w - c.w;
    float s = dx * dx + dy * dy + dz * dz + dw * dw;
    #pragma unroll
    for (int off = 32; off; off >>= 1) s += __shfl_xor(s, off);
    if (l == 0) sblk[w] = s;
    __syncthreads();
    if (threadIdx.x == 0)
        partial[blockIdx.x] = sblk[0] + sblk[1] + sblk[2] + sblk[3];
}

// ---------------------------------------------------------------- kernel 4
__global__ void k_write(const float* __restrict__ partial,
                        float* __restrict__ out) {
    __shared__ float swv[16];
    int tid = threadIdx.x;                    // 1024 threads = 16 waves
    float s = partial[tid] + partial[tid + 1024] +
              partial[tid + 2048] + partial[tid + 3072];
    #pragma unroll
    for (int off = 32; off; off >>= 1) s += __shfl_xor(s, off);
    if ((tid & 63) == 0) swv[tid >> 6] = s;
    __syncthreads();
    if (tid == 0) {
        float t = 0.0f;
        #pragma unroll
        for (int i = 0; i < 16; i++) t += swv[i];
        float commit = t * INV_N;
        out[0] = 0.25f * commit;   // loss
        out[1] = commit;           // commit_loss
    }
}

extern "C" void kernel_launch(void* const* d_in, const int* in_sizes, int n_in,
                              void* d_out, int out_size, void* d_ws, size_t ws_size,
                              hipStream_t stream) {
    const float* xs = (const float*)d_in[0];
    // d_in[1] = ilens (int64, all == T) -> slice is a no-op, unused
    const float* cb = (const float*)d_in[2];

    char* ws = (char*)d_ws;
    unsigned char* cbt     = (unsigned char*)(ws + 256);            // 2 MiB
    float*         chalf   = (float*)(ws + 256 + 2097152);          // 32 KiB
    uint32_t*      pkey    = (uint32_t*)(ws + 256 + 2129920);       // 512 KiB
    float*         partial = (float*)(ws + 256 + 2654208);          // 16 KiB

    k_prep<<<128, 256, 0, stream>>>(cb, cbt, chalf);
    dim3 g(M_TOK / 128, NGRP);
    k_gemm_argmin<<<g, 256, 0, stream>>>(xs, cbt, chalf, pkey);
    k_finalize<<<4096, 256, 0, stream>>>(pkey, (const float4*)xs,
                                         (const float4*)cb, partial);
    k_write<<<1, 1024, 0, stream>>>(partial, (float*)d_out);
}